// Round 1
// 540.118 us; speedup vs baseline: 1.0033x; 1.0033x over previous
//
#include <hip/hip_runtime.h>

typedef unsigned short u16;
typedef unsigned int u32;
typedef __bf16 bf16x8 __attribute__((ext_vector_type(8)));
typedef float f32x4 __attribute__((ext_vector_type(4)));

// Problem constants: B=4, N=2048, C=2048, H=16, DH=128
// tokens BN = 8192, qkv row = 3*C = 6144

__device__ __forceinline__ u16 f2bf(float f) {
    u32 u = __builtin_bit_cast(u32, f);
    u += 0x7FFFu + ((u >> 16) & 1u);   // round-to-nearest-even
    return (u16)(u >> 16);
}
__device__ __forceinline__ float bf2f(u16 h) {
    return __builtin_bit_cast(float, ((u32)h) << 16);
}

// ---------------- fp32 -> bf16 conversion (vectorized) ----------------
__global__ __launch_bounds__(256) void cvt_bf16(const float* __restrict__ in,
                                                u16* __restrict__ out, int n4) {
    int i = blockIdx.x * 256 + threadIdx.x;
    if (i >= n4) return;
    const float4 f = reinterpret_cast<const float4*>(in)[i];
    ushort4 o;
    o.x = f2bf(f.x); o.y = f2bf(f.y); o.z = f2bf(f.z); o.w = f2bf(f.w);
    reinterpret_cast<ushort4*>(out)[i] = o;
}

// ---------------- async global->LDS copy, 16 B per lane ----------------
typedef const __attribute__((address_space(1))) void* gas1_t;
typedef __attribute__((address_space(3))) void* las3_t;
__device__ __forceinline__ void cp16(const void* g, void* l) {
    __builtin_amdgcn_global_load_lds((gas1_t)g, (las3_t)l, 16, 0, 0);
}

#define BAR()        __builtin_amdgcn_s_barrier()
#define WAIT_LGKM0() asm volatile("s_waitcnt lgkmcnt(0)" ::: "memory")
#define WAIT_VM6()   asm volatile("s_waitcnt vmcnt(6)" ::: "memory")
#define WAIT_VM0()   asm volatile("s_waitcnt vmcnt(0)" ::: "memory")

// ==================== 256x256 8-phase bf16 NT GEMM ====================
// C = A(MxK) * B(NxK)^T + bias.  BM=BN=256, BK=64, 512 threads = 8 waves (2Mx4N),
// per-wave output 128x64, MFMA 16x16x32 (acc f32x4[8][4] = 128 VGPR).
//
// LDS (128 KiB, double-buffered): per matrix, per buf, per 128-row half:
//   granule(kc 0..7, r 0..127) of 16 B (8 bf16 along K) at kc*2048 + r*16.
// k-chunk-major => a wave's frag ds_read_b128 is 16 consecutive granules per
// 16-lane group -> 2 lanes/bank (conflict-free, m136).  global_load_lds dest is
// linear (tid*16); the permutation lives in the per-lane GLOBAL src (m173).
//
// 8 phases per iteration (2 K-tiles T=2i in buf0, T+1 in buf1); each phase:
//   {ds_read frag subtile | stage half-tile(s)} ; barrier ; lgkmcnt(0) ;
//   setprio(1) ; 16 MFMA (one C quadrant x K=64) ; setprio(0) ; barrier
// Quadrant order (mh,nh): (0,0),(0,1),(1,0),(1,1).  Reads: ph1: A mt0-3 + B nt0-1
// (12), ph2: B nt2-3 (4), ph3: A mt4-7 (8), ph4: none.  So per buffer: B last
// read ph2, A last read ph3.
// Stage schedule (each targets a region whose last read was a previous phase,
// hence formally race-free: readers pass lgkmcnt(0) before the barrier that
// releases the staging phase):
//   ph1: (T+1)A-h1 -> buf1      ph5: (T+2)A-h1 -> buf0
//   ph3: (T+2)B-h0,B-h1 -> buf0 ph7: (T+3)B-h0,B-h1 -> buf1
//   ph4: (T+2)A-h0 -> buf0      ph8: (T+3)A-h0 -> buf1
// vmcnt(6) at end of ph4/ph8 leaves exactly the 3 newest half-tiles (6 loads)
// in flight (T4 counted-vmcnt; never drain to 0 in the loop).
// Tail: prefetch tile index wraps mod NT (harmless in-bounds loads).

__device__ __forceinline__ void ld_a4(bf16x8 (&a)[4][2], const char* rdA, int off, int mt0) {
#pragma unroll
    for (int i = 0; i < 4; ++i) {
        a[i][0] = *(const bf16x8*)(rdA + off +        (mt0 + i) * 256);
        a[i][1] = *(const bf16x8*)(rdA + off + 8192 + (mt0 + i) * 256);
    }
}
__device__ __forceinline__ void ld_b2(bf16x8 (&b)[4][2], const char* rdB, int off, int nt0) {
#pragma unroll
    for (int j = 0; j < 2; ++j) {
        b[nt0 + j][0] = *(const bf16x8*)(rdB + off +        (nt0 + j) * 256);
        b[nt0 + j][1] = *(const bf16x8*)(rdB + off + 8192 + (nt0 + j) * 256);
    }
}

template <int MH, int NH>
__device__ __forceinline__ void mfma_quad(f32x4 (&acc)[8][4], bf16x8 (&a)[4][2], bf16x8 (&b)[4][2]) {
    __builtin_amdgcn_s_setprio(1);
#pragma unroll
    for (int ks = 0; ks < 2; ++ks)
#pragma unroll
        for (int i = 0; i < 4; ++i)
#pragma unroll
            for (int j = 0; j < 2; ++j)
                acc[MH * 4 + i][NH * 2 + j] = __builtin_amdgcn_mfma_f32_16x16x32_bf16(
                    a[i][ks], b[NH * 2 + j][ks], acc[MH * 4 + i][NH * 2 + j], 0, 0, 0);
    __builtin_amdgcn_s_setprio(0);
}

template <int OUT_BF16>
__global__ __launch_bounds__(512, 2) void gemm_nt(const u16* __restrict__ A,
                                                  const u16* __restrict__ Bm,
                                                  const float* __restrict__ bias,
                                                  void* __restrict__ Cout,
                                                  int M, int N, int K) {
    // [A | B] each 64 KiB: buf*32768 + half*16384 + kc*2048 + r*16
    __shared__ __align__(16) char lds[131072];

    const int tid  = threadIdx.x;
    const int lane = tid & 63;
    const int wave = tid >> 6;
    const int wm   = wave >> 2;     // 0..1  (M position of wave)
    const int wn   = wave & 3;      // 0..3  (N position)
    const int l16  = lane & 15;
    const int kg   = lane >> 4;     // 0..3  (k-group within frag)

    const long bm = (long)blockIdx.y * 256;
    const long bn = (long)blockIdx.x * 256;

    // ---- staging source pointers: thread t stages granules t and t+512 of a
    // half-tile => (r = t&127, kc = (t>>7) and (t>>7)+4); LDS dest = tid*16. ----
    const int srow = tid & 127;
    const int skc  = tid >> 7;      // 0..3
    const u16* gA0 = A  + (bm + srow) * (long)K + skc * 8;
    const u16* gA1 = gA0 + 128 * (long)K;
    const u16* gB0 = Bm + (bn + srow) * (long)K + skc * 8;
    const u16* gB1 = gB0 + 128 * (long)K;
    char* ldst = lds + tid * 16;

#define STAGE_A(HALF, BUF, KT)                                    \
    { const u16* g = ((HALF) ? gA1 : gA0) + (KT) * 64;            \
      char* d = ldst + (BUF) * 32768 + (HALF) * 16384;            \
      cp16(g, d); cp16(g + 32, d + 8192); }
#define STAGE_B(HALF, BUF, KT)                                    \
    { const u16* g = ((HALF) ? gB1 : gB0) + (KT) * 64;            \
      char* d = ldst + 65536 + (BUF) * 32768 + (HALF) * 16384;    \
      cp16(g, d); cp16(g + 32, d + 8192); }

    // ---- frag read base addresses (add buf*32768 + ks*8192 + tile*256) ----
    const char* rdA = lds + wm * 16384 + kg * 2048 + l16 * 16;
    const char* rdB = lds + 65536 + (wn >> 1) * 16384 + kg * 2048
                      + ((wn & 1) * 64 + l16) * 16;

    f32x4 acc[8][4];
#pragma unroll
    for (int i = 0; i < 8; ++i)
#pragma unroll
        for (int j = 0; j < 4; ++j)
#pragma unroll
            for (int r = 0; r < 4; ++r) acc[i][j][r] = 0.f;

    const int NT = K >> 6;      // 64-wide K tiles (32 for K=2048)

    // ---- prologue: tile0 full + tile1 {B0,B1,A0}; leave 3 halves in flight ----
    STAGE_B(0, 0, 0); STAGE_B(1, 0, 0); STAGE_A(0, 0, 0); STAGE_A(1, 0, 0);
    STAGE_B(0, 1, 1); STAGE_B(1, 1, 1); STAGE_A(0, 1, 1);
    WAIT_VM6();
    BAR();

    bf16x8 a[4][2], b[4][2];

#define KTILE(RBUF, A1B, A1K, BB, BKT, A0B, A0K)                  \
    {                                                             \
        const int ro = (RBUF) * 32768;                            \
        /* phase A: quadrant (0,0) */                             \
        ld_a4(a, rdA, ro, 0);                                     \
        ld_b2(b, rdB, ro, 0);                                     \
        STAGE_A(1, A1B, A1K);                                     \
        BAR(); WAIT_LGKM0();                                      \
        mfma_quad<0, 0>(acc, a, b);                               \
        BAR();                                                    \
        /* phase B: quadrant (0,1) */                             \
        ld_b2(b, rdB, ro, 2);                                     \
        BAR(); WAIT_LGKM0();                                      \
        mfma_quad<0, 1>(acc, a, b);                               \
        BAR();                                                    \
        /* phase C: quadrant (1,0) */                             \
        ld_a4(a, rdA, ro, 4);                                     \
        STAGE_B(0, BB, BKT); STAGE_B(1, BB, BKT);                 \
        BAR(); WAIT_LGKM0();                                      \
        mfma_quad<1, 0>(acc, a, b);                               \
        BAR();                                                    \
        /* phase D: quadrant (1,1) */                             \
        STAGE_A(0, A0B, A0K);                                     \
        BAR(); WAIT_LGKM0();                                      \
        mfma_quad<1, 1>(acc, a, b);                               \
        WAIT_VM6();                                               \
        BAR();                                                    \
    }

    const int NIT = NT >> 1;
    for (int it = 0; it < NIT; ++it) {
        const int T = 2 * it;
        int t2 = T + 2; if (t2 >= NT) t2 -= NT;
        int t3 = T + 3; if (t3 >= NT) t3 -= NT;
        KTILE(0, /*A1->*/1, T + 1, /*B->*/0, t2, /*A0->*/0, t2);   // phases 1-4
        KTILE(1, /*A1->*/0, t2,    /*B->*/1, t3, /*A0->*/1, t3);   // phases 5-8
    }
#undef KTILE
#undef STAGE_A
#undef STAGE_B

    WAIT_VM0();   // drain wasted tail prefetches before epilogue vmem

    // ---- epilogue: C/D 16x16 layout col=lane&15, row=(lane>>4)*4+reg ----
    const long crow0 = bm + wm * 128;
    const long ccol0 = bn + wn * 64 + l16;
#pragma unroll
    for (int nt = 0; nt < 4; ++nt) {
        const long col = ccol0 + nt * 16;
        const float bc = bias[col];
#pragma unroll
        for (int mt = 0; mt < 8; ++mt) {
#pragma unroll
            for (int r = 0; r < 4; ++r) {
                const long row = crow0 + mt * 16 + kg * 4 + r;
                float v = acc[mt][nt][r] + bc;
                if (OUT_BF16)
                    ((u16*)Cout)[row * (long)N + col] = f2bf(v);
                else
                    ((float*)Cout)[row * (long)N + col] = v;
            }
        }
    }
}

// ---------------- per-token head-mixing attention ----------------
// One block (256 thr) per token. q,k,v: 16x128 each from qkv row (3*2048 bf16).
// S = q k^T / sqrt(2048) (16x16), softmax rows, O = S v (16x128).
// Write O to scrambled layout: row h*128 + n/16, col (n%16)*128 + d (bf16).
__global__ __launch_bounds__(256) void attn(const u16* __restrict__ qkv,
                                            u16* __restrict__ outb) {
    __shared__ float sQ[16 * 132];   // +4 pad: stride 132 floats kills bank conflicts
    __shared__ float sK[16 * 132];
    __shared__ float sV[16 * 132];
    __shared__ float sP[16 * 17];

    const int tid = threadIdx.x;
    const int token = blockIdx.x;
    const int b = token >> 11;      // /2048
    const int n = token & 2047;
    const u16* row = qkv + (long)token * 6144;

    // ---- load q,k,v -> LDS as fp32 (each thread: 8 contiguous elems) ----
    {
        const int r  = tid >> 4;          // 0..15
        const int c8 = (tid & 15) * 8;    // 0,8,...,120
#pragma unroll
        for (int m = 0; m < 3; ++m) {
            const uint4 u = *reinterpret_cast<const uint4*>(row + m * 2048 + tid * 8);
            float* dst = (m == 0 ? sQ : (m == 1 ? sK : sV)) + r * 132 + c8;
            float4 lo, hi;
            lo.x = bf2f((u16)u.x); lo.y = bf2f((u16)(u.x >> 16));
            lo.z = bf2f((u16)u.y); lo.w = bf2f((u16)(u.y >> 16));
            hi.x = bf2f((u16)u.z); hi.y = bf2f((u16)(u.z >> 16));
            hi.z = bf2f((u16)u.w); hi.w = bf2f((u16)(u.w >> 16));
            *reinterpret_cast<float4*>(dst)     = lo;
            *reinterpret_cast<float4*>(dst + 4) = hi;
        }
    }
    __syncthreads();

    // ---- S + softmax: thread (h,g) = (tid>>4, tid&15); 16-lane-group reductions ----
    {
        const int h = tid >> 4, g = tid & 15;
        const float4* qr = reinterpret_cast<const float4*>(&sQ[h * 132]);
        const float4* kr = reinterpret_cast<const float4*>(&sK[g * 132]);
        float s = 0.f;
#pragma unroll
        for (int d = 0; d < 32; ++d) {
            const float4 a = qr[d], k4 = kr[d];
            s += a.x * k4.x + a.y * k4.y + a.z * k4.z + a.w * k4.w;
        }
        s *= 0.022097086912079608f;   // 1/sqrt(2048)
        float mx = s;
#pragma unroll
        for (int o = 8; o >= 1; o >>= 1) mx = fmaxf(mx, __shfl_xor(mx, o, 16));
        const float e = __expf(s - mx);
        float sum = e;
#pragma unroll
        for (int o = 8; o >= 1; o >>= 1) sum += __shfl_xor(sum, o, 16);
        sP[h * 17 + g] = e / sum;
    }
    __syncthreads();

    // ---- O = P @ V; thread (h, dblk) handles d = dblk*8 .. +7 ----
    {
        const int h = tid >> 4, dblk = tid & 15;
        float p[16];
#pragma unroll
        for (int g = 0; g < 16; ++g) p[g] = sP[h * 17 + g];
        float4 o0 = {0.f, 0.f, 0.f, 0.f}, o1 = {0.f, 0.f, 0.f, 0.f};
#pragma unroll
        for (int g = 0; g < 16; ++g) {
            const float* vr = &sV[g * 132 + dblk * 8];
            const float4 v0 = *reinterpret_cast<const float4*>(vr);
            const float4 v1 = *reinterpret_cast<const float4*>(vr + 4);
            o0.x += p[g] * v0.x; o0.y += p[g] * v0.y; o0.z += p[g] * v0.z; o0.w += p[g] * v0.w;
            o1.x += p[g] * v1.x; o1.y += p[g] * v1.y; o1.z += p[g] * v1.z; o1.w += p[g] * v1.w;
        }
        // scrambled reshape target: row = h*128 + n/16, col = (n%16)*128 + d
        const long rr = (long)h * 128 + (n >> 4);
        const long cc = (long)(n & 15) * 128 + dblk * 8;
        u16* dst = outb + ((long)b * 2048 + rr) * 2048 + cc;
        uint4 pk;
        pk.x = (u32)f2bf(o0.x) | ((u32)f2bf(o0.y) << 16);
        pk.y = (u32)f2bf(o0.z) | ((u32)f2bf(o0.w) << 16);
        pk.z = (u32)f2bf(o1.x) | ((u32)f2bf(o1.y) << 16);
        pk.w = (u32)f2bf(o1.z) | ((u32)f2bf(o1.w) << 16);
        *reinterpret_cast<uint4*>(dst) = pk;
    }
}

// ---------------- launch ----------------
extern "C" void kernel_launch(void* const* d_in, const int* in_sizes, int n_in,
                              void* d_out, int out_size, void* d_ws, size_t ws_size,
                              hipStream_t stream) {
    const float* x     = (const float*)d_in[0];   // (4,2048,2048)
    const float* w_qkv = (const float*)d_in[1];   // (6144,2048)
    const float* b_qkv = (const float*)d_in[2];   // (6144,)
    const float* w_out = (const float*)d_in[3];   // (2048,2048)
    const float* b_out = (const float*)d_in[4];   // (2048,)
    float* out = (float*)d_out;                   // (4,2048,2048) fp32

    char* ws = (char*)d_ws;
    // workspace layout (bytes):
    //   xb    @ 0          : 8192*2048*2  = 33554432
    //   wqkvb @ 33554432   : 6144*2048*2  = 25165824
    //   woutb @ 58720256   : 2048*2048*2  =  8388608
    //   qkvb  @ 67108864   : 8192*6144*2  = 100663296   (end 167772160)
    //   attnb aliases xb (x no longer needed after GEMM1)
    u16* xb    = (u16*)(ws);
    u16* wqkvb = (u16*)(ws + 33554432);
    u16* woutb = (u16*)(ws + 58720256);
    u16* qkvb  = (u16*)(ws + 67108864);
    u16* attnb = xb;

    cvt_bf16<<<16384, 256, 0, stream>>>(x,     xb,    16777216 / 4);
    cvt_bf16<<<12288, 256, 0, stream>>>(w_qkv, wqkvb, 12582912 / 4);
    cvt_bf16<<<4096,  256, 0, stream>>>(w_out, woutb, 4194304 / 4);

    dim3 g1(24, 32);  // N/256, M/256
    gemm_nt<1><<<g1, 512, 0, stream>>>(xb, wqkvb, b_qkv, qkvb, 8192, 6144, 2048);

    attn<<<8192, 256, 0, stream>>>(qkvb, attnb);

    dim3 g2(8, 32);   // N/256, M/256
    gemm_nt<0><<<g2, 512, 0, stream>>>(attnb, woutb, b_out, out, 8192, 2048, 2048);
}